// Round 2
// baseline (257.121 us; speedup 1.0000x reference)
//
#include <hip/hip_runtime.h>

#define DIM 16
#define NE 120            // edges in the Clements mesh for MODES=16
#define ITEMS 4           // batch items per block (one wave)
#define THREADS 64
#define USTRIDE 20        // U row stride (floats) -> 80B rows, 16B aligned
#define UITEM 648         // per-item LDS floats (== 8 mod 32 -> groups on distinct bank quartets)
#define LDS_FLOATS (ITEMS * UITEM)   // 2592 floats = 10368 B

__global__ __launch_bounds__(THREADS, 4) void uparam_kernel(
    const float* __restrict__ params,
    const float* __restrict__ state_re,
    const float* __restrict__ state_im,
    float* __restrict__ out)
{
    __shared__ float lds[LDS_FLOATS];

    const int tid  = threadIdx.x;
    const int item = tid >> 4;     // 0..3 within block (= wave)
    const int r    = tid & 15;     // column during build, row during matmuls
    const long b   = (long)blockIdx.x * ITEMS + item;

    float* slot = lds + item * UITEM;   // holds cs-table first, then U

    // ---------- Phase P: cooperative sincos table ---------------------------
    // Lane r of each group computes angles a = k*16 + r (k=0..14), coalesced
    // global reads. Record layout per edge e: slot[4e..4e+3] = {ct, st, cp, sp}.
    {
        const float* prow = params + b * (2 * NE);
        #pragma unroll
        for (int k = 0; k < 15; ++k) {
            const int a = k * 16 + r;
            const float ang = prow[a];
            float s, c;
            __sincosf(ang, &s, &c);
            const int e   = (a < NE) ? a : a - NE;
            const int off = (a < NE) ? 0 : 2;
            *(float2*)(slot + e * 4 + off) = make_float2(c, s);
        }
    }
    __syncthreads();

    // ---------- Phase B: build U column `r` in registers --------------------
    float Ur[DIM], Ui[DIM];
    #pragma unroll
    for (int i = 0; i < DIM; ++i) { Ur[i] = (i == r) ? 1.0f : 0.0f; Ui[i] = 0.0f; }

    #pragma unroll 1
    for (int l2 = 0; l2 < 8; ++l2) {
        const int eb = l2 * 15;   // 8 even-layer + 7 odd-layer edges per pair
        // even layer: pairs (0,1),(2,3)...(14,15)
        #pragma unroll
        for (int j = 0; j < 8; ++j) {
            const int m = 2 * j, n = m + 1;
            const float4 cs = *(const float4*)(slot + (eb + j) * 4);
            const float c = cs.x, s = cs.y, cp = cs.z, sp = cs.w;
            const float rmr = Ur[m], rmi = Ui[m], rnr = Ur[n], rni = Ui[n];
            const float ecr = cp * c, eci = sp * c, esr = cp * s, esi = sp * s;
            Ur[m] = ecr * rmr - eci * rmi - s * rnr;
            Ui[m] = ecr * rmi + eci * rmr - s * rni;
            Ur[n] = esr * rmr - esi * rmi + c * rnr;
            Ui[n] = esr * rmi + esi * rmr + c * rni;
        }
        // odd layer: pairs (1,2),(3,4)...(13,14)
        #pragma unroll
        for (int j = 0; j < 7; ++j) {
            const int m = 2 * j + 1, n = m + 1;
            const float4 cs = *(const float4*)(slot + (eb + 8 + j) * 4);
            const float c = cs.x, s = cs.y, cp = cs.z, sp = cs.w;
            const float rmr = Ur[m], rmi = Ui[m], rnr = Ur[n], rni = Ui[n];
            const float ecr = cp * c, eci = sp * c, esr = cp * s, esi = sp * s;
            Ur[m] = ecr * rmr - eci * rmi - s * rnr;
            Ui[m] = ecr * rmi + eci * rmr - s * rni;
            Ur[n] = esr * rmr - esi * rmi + c * rnr;
            Ui[n] = esr * rmi + esi * rmr + c * rni;
        }
    }

    __syncthreads();   // cs-table fully consumed; safe to overwrite with U

    // ---------- write U (this lane's column) to LDS --------------------------
    #pragma unroll
    for (int i = 0; i < DIM; ++i) {
        slot[i * USTRIDE + r] = Ur[i];
        slot[DIM * USTRIDE + i * USTRIDE + r] = Ui[i];
    }
    __syncthreads();

    // ---------- Phase C: left row r = U[r][:] * rho --------------------------
    float Lr[DIM], Li[DIM];
    #pragma unroll
    for (int k = 0; k < DIM; ++k) { Lr[k] = 0.f; Li[k] = 0.f; }

    const float4* rhor = (const float4*)(state_re + b * (DIM * DIM));
    const float4* rhoi = (const float4*)(state_im + b * (DIM * DIM));
    const float* Urow_r = slot + r * USTRIDE;
    const float* Urow_i = slot + DIM * USTRIDE + r * USTRIDE;

    #pragma unroll 1
    for (int j4 = 0; j4 < 4; ++j4) {
        const float4 u4r = *(const float4*)(Urow_r + j4 * 4);
        const float4 u4i = *(const float4*)(Urow_i + j4 * 4);
        const float uar[4] = { u4r.x, u4r.y, u4r.z, u4r.w };
        const float uai[4] = { u4i.x, u4i.y, u4i.z, u4i.w };
        #pragma unroll
        for (int jj = 0; jj < 4; ++jj) {
            const int j = j4 * 4 + jj;
            const float ur = uar[jj], ui = uai[jj];
            #pragma unroll
            for (int k4 = 0; k4 < 4; ++k4) {
                const float4 pr = rhor[j * 4 + k4];
                const float4 pi = rhoi[j * 4 + k4];
                Lr[k4*4+0] += ur * pr.x - ui * pi.x;  Li[k4*4+0] += ur * pi.x + ui * pr.x;
                Lr[k4*4+1] += ur * pr.y - ui * pi.y;  Li[k4*4+1] += ur * pi.y + ui * pr.y;
                Lr[k4*4+2] += ur * pr.z - ui * pi.z;  Li[k4*4+2] += ur * pi.z + ui * pr.z;
                Lr[k4*4+3] += ur * pr.w - ui * pi.w;  Li[k4*4+3] += ur * pi.w + ui * pr.w;
            }
        }
    }

    // ---------- Phase D: out[r][j] = sum_k left[k] * conj(U[j][k]) -----------
    float* outp = out + b * (2 * DIM * DIM) + r * DIM;
    #pragma unroll 1
    for (int jj = 0; jj < 4; ++jj) {
        float orr[4], oii[4];
        #pragma unroll
        for (int j4 = 0; j4 < 4; ++j4) {
            const int j = jj * 4 + j4;
            const float* Uj_r = slot + j * USTRIDE;
            const float* Uj_i = slot + DIM * USTRIDE + j * USTRIDE;
            float ar = 0.f, ai = 0.f;
            #pragma unroll
            for (int k4 = 0; k4 < 4; ++k4) {
                const float4 ur4 = *(const float4*)(Uj_r + k4 * 4);
                const float4 ui4 = *(const float4*)(Uj_i + k4 * 4);
                ar += Lr[k4*4+0] * ur4.x + Li[k4*4+0] * ui4.x;
                ai += Li[k4*4+0] * ur4.x - Lr[k4*4+0] * ui4.x;
                ar += Lr[k4*4+1] * ur4.y + Li[k4*4+1] * ui4.y;
                ai += Li[k4*4+1] * ur4.y - Lr[k4*4+1] * ui4.y;
                ar += Lr[k4*4+2] * ur4.z + Li[k4*4+2] * ui4.z;
                ai += Li[k4*4+2] * ur4.z - Lr[k4*4+2] * ui4.z;
                ar += Lr[k4*4+3] * ur4.w + Li[k4*4+3] * ui4.w;
                ai += Li[k4*4+3] * ur4.w - Lr[k4*4+3] * ui4.w;
            }
            orr[j4] = ar; oii[j4] = ai;
        }
        *(float4*)(outp + jj * 4) = make_float4(orr[0], orr[1], orr[2], orr[3]);
        *(float4*)(outp + DIM * DIM + jj * 4) = make_float4(oii[0], oii[1], oii[2], oii[3]);
    }
}

extern "C" void kernel_launch(void* const* d_in, const int* in_sizes, int n_in,
                              void* d_out, int out_size, void* d_ws, size_t ws_size,
                              hipStream_t stream) {
    const float* params   = (const float*)d_in[0];
    const float* state_re = (const float*)d_in[1];
    const float* state_im = (const float*)d_in[2];
    // d_in[3] = targets; structure is the fixed Clements mesh, derived in-kernel.
    float* out = (float*)d_out;

    const int batch = in_sizes[0] / (2 * NE);   // 32768
    dim3 grid(batch / ITEMS);                   // 8192 blocks, 1 wave each
    uparam_kernel<<<grid, THREADS, 0, stream>>>(params, state_re, state_im, out);
}

// Round 3
// 161.330 us; speedup vs baseline: 1.5938x; 1.5938x over previous
//
#include <hip/hip_runtime.h>

#define DIM 16
#define NE 120            // edges in the Clements mesh for MODES=16
#define ITEMS 16          // batch items per block
#define THREADS 256
#define USTRIDE 20        // U row stride (floats) -> 80B rows, 16B aligned
#define UITEM 648         // per-item LDS floats (== 8 mod 32 -> conflict-free group offsets)
#define LDS_FLOATS (ITEMS * UITEM)   // 10368 floats = 41472 B -> 3 blocks/CU

// Per-item slot layout (lifetimes overlap, cs-table dead before U is written):
//   phase P/B: cs-table  A[e] = slot[2e..2e+1]      = {cos(theta_e), sin(theta_e)}
//                        B[e] = slot[240+2e..+1]    = {cos(phi_e),  sin(phi_e)}
//   phase C/D: U         Ure[i] at slot[i*20 + c], Uim[i] at slot[320 + i*20 + c]

__global__ __launch_bounds__(THREADS, 3) void uparam_kernel(
    const float* __restrict__ params,
    const float* __restrict__ state_re,
    const float* __restrict__ state_im,
    float* __restrict__ out)
{
    __shared__ float lds[LDS_FLOATS];

    const int tid  = threadIdx.x;
    const int item = tid >> 4;     // 0..15 within block
    const int r    = tid & 15;     // column during build, row during matmuls
    const long b   = (long)blockIdx.x * ITEMS + item;

    float* slot = lds + item * UITEM;

    // ---------- Phase P: cooperative block-wide sincos table ----------------
    // 3840 angles per block; each thread does 15, reads fully coalesced.
    {
        const float* src = params + (long)blockIdx.x * ITEMS * (2 * NE);
        #pragma unroll
        for (int k = 0; k < 15; ++k) {
            const int idx = k * THREADS + tid;
            const int it  = idx / (2 * NE);
            const int a   = idx - it * (2 * NE);
            const float ang = src[idx];
            float s, c;
            __sincosf(ang, &s, &c);
            const int e   = (a < NE) ? a : a - NE;
            const int off = (a < NE) ? 2 * e : 2 * NE + 2 * e;
            *(float2*)(lds + it * UITEM + off) = make_float2(c, s);
        }
    }
    __syncthreads();

    // ---------- Phase B: build U column `r` in registers --------------------
    float Ur[DIM], Ui[DIM];
    #pragma unroll
    for (int i = 0; i < DIM; ++i) { Ur[i] = (i == r) ? 1.0f : 0.0f; Ui[i] = 0.0f; }

    #pragma unroll 1
    for (int l2 = 0; l2 < 8; ++l2) {
        const int eb = l2 * 15;   // 8 even-layer + 7 odd-layer edges per layer pair
        #pragma unroll
        for (int j = 0; j < 15; ++j) {
            // j<8: even layer pair (2j, 2j+1); j>=8: odd layer pair (2(j-8)+1, +2)
            const int m = (j < 8) ? 2 * j : 2 * (j - 8) + 1;
            const int n = m + 1;
            const int e = eb + j;
            const float2 ts = *(const float2*)(slot + 2 * e);            // cos t, sin t
            const float2 ps = *(const float2*)(slot + 2 * NE + 2 * e);   // cos p, sin p
            const float c = ts.x, s = ts.y, cp = ps.x, sp = ps.y;
            const float rmr = Ur[m], rmi = Ui[m], rnr = Ur[n], rni = Ui[n];
            // w = e^{i phi} * rm
            const float wr = cp * rmr - sp * rmi;
            const float wi = cp * rmi + sp * rmr;
            Ur[m] = c * wr - s * rnr;
            Ui[m] = c * wi - s * rni;
            Ur[n] = s * wr + c * rnr;
            Ui[n] = s * wi + c * rni;
        }
    }

    __syncthreads();   // cs-table fully consumed; safe to overwrite with U

    // ---------- write U (this lane's column) to LDS --------------------------
    #pragma unroll
    for (int i = 0; i < DIM; ++i) {
        slot[i * USTRIDE + r] = Ur[i];
        slot[DIM * USTRIDE + i * USTRIDE + r] = Ui[i];
    }
    __syncthreads();

    // ---------- Phase C: left row r = U[r][:] * rho --------------------------
    float Lr[DIM], Li[DIM];
    #pragma unroll
    for (int k = 0; k < DIM; ++k) { Lr[k] = 0.f; Li[k] = 0.f; }

    const float4* rhor = (const float4*)(state_re + b * (DIM * DIM));
    const float4* rhoi = (const float4*)(state_im + b * (DIM * DIM));
    const float* Urow_r = slot + r * USTRIDE;
    const float* Urow_i = slot + DIM * USTRIDE + r * USTRIDE;

    #pragma unroll 1
    for (int j4 = 0; j4 < 4; ++j4) {
        const float4 u4r = *(const float4*)(Urow_r + j4 * 4);
        const float4 u4i = *(const float4*)(Urow_i + j4 * 4);
        const float uar[4] = { u4r.x, u4r.y, u4r.z, u4r.w };
        const float uai[4] = { u4i.x, u4i.y, u4i.z, u4i.w };
        #pragma unroll
        for (int jj = 0; jj < 4; ++jj) {
            const int j = j4 * 4 + jj;
            const float ur = uar[jj], ui = uai[jj];
            #pragma unroll
            for (int k4 = 0; k4 < 4; ++k4) {
                const float4 pr = rhor[j * 4 + k4];
                const float4 pi = rhoi[j * 4 + k4];
                Lr[k4*4+0] += ur * pr.x - ui * pi.x;  Li[k4*4+0] += ur * pi.x + ui * pr.x;
                Lr[k4*4+1] += ur * pr.y - ui * pi.y;  Li[k4*4+1] += ur * pi.y + ui * pr.y;
                Lr[k4*4+2] += ur * pr.z - ui * pi.z;  Li[k4*4+2] += ur * pi.z + ui * pr.z;
                Lr[k4*4+3] += ur * pr.w - ui * pi.w;  Li[k4*4+3] += ur * pi.w + ui * pr.w;
            }
        }
    }

    // ---------- Phase D: out[r][j] = sum_k left[k] * conj(U[j][k]) -----------
    float* outp = out + b * (2 * DIM * DIM) + r * DIM;
    #pragma unroll 1
    for (int jj = 0; jj < 4; ++jj) {
        float orr[4], oii[4];
        #pragma unroll
        for (int j4 = 0; j4 < 4; ++j4) {
            const int j = jj * 4 + j4;
            const float* Uj_r = slot + j * USTRIDE;
            const float* Uj_i = slot + DIM * USTRIDE + j * USTRIDE;
            float ar = 0.f, ai = 0.f;
            #pragma unroll
            for (int k4 = 0; k4 < 4; ++k4) {
                const float4 ur4 = *(const float4*)(Uj_r + k4 * 4);
                const float4 ui4 = *(const float4*)(Uj_i + k4 * 4);
                ar += Lr[k4*4+0] * ur4.x + Li[k4*4+0] * ui4.x;
                ai += Li[k4*4+0] * ur4.x - Lr[k4*4+0] * ui4.x;
                ar += Lr[k4*4+1] * ur4.y + Li[k4*4+1] * ui4.y;
                ai += Li[k4*4+1] * ur4.y - Lr[k4*4+1] * ui4.y;
                ar += Lr[k4*4+2] * ur4.z + Li[k4*4+2] * ui4.z;
                ai += Li[k4*4+2] * ur4.z - Lr[k4*4+2] * ui4.z;
                ar += Lr[k4*4+3] * ur4.w + Li[k4*4+3] * ui4.w;
                ai += Li[k4*4+3] * ur4.w - Lr[k4*4+3] * ui4.w;
            }
            orr[j4] = ar; oii[j4] = ai;
        }
        *(float4*)(outp + jj * 4) = make_float4(orr[0], orr[1], orr[2], orr[3]);
        *(float4*)(outp + DIM * DIM + jj * 4) = make_float4(oii[0], oii[1], oii[2], oii[3]);
    }
}

extern "C" void kernel_launch(void* const* d_in, const int* in_sizes, int n_in,
                              void* d_out, int out_size, void* d_ws, size_t ws_size,
                              hipStream_t stream) {
    const float* params   = (const float*)d_in[0];
    const float* state_re = (const float*)d_in[1];
    const float* state_im = (const float*)d_in[2];
    // d_in[3] = targets; structure is the fixed Clements mesh, derived in-kernel.
    float* out = (float*)d_out;

    const int batch = in_sizes[0] / (2 * NE);   // 32768
    dim3 grid(batch / ITEMS);                   // 2048 blocks
    uparam_kernel<<<grid, THREADS, 0, stream>>>(params, state_re, state_im, out);
}

// Round 4
// 135.345 us; speedup vs baseline: 1.8997x; 1.1920x over previous
//
#include <hip/hip_runtime.h>

#define DIM 16
#define NE 120            // edges in the Clements mesh for MODES=16
#define ITEMS 8           // batch items per block
#define THREADS 128
#define USTRIDE 20        // U row stride (floats) -> 80B rows, 16B aligned
#define UITEM 648         // per-item LDS floats (== 8 mod 32 -> conflict-free group offsets)
#define LDS_FLOATS (ITEMS * UITEM)   // 5184 floats = 20736 B -> 7 blocks/CU

// Per-item slot layout (lifetimes overlap; cs-table dead before U is written):
//   phase P/B: cs-table record e: slot[4e..4e+3] = {cos t, sin t, cos p, sin p}  (480 floats)
//   phase C/D: U: Ure[i] at slot[i*20 + c], Uim[i] at slot[320 + i*20 + c]       (640 floats)

__global__ __launch_bounds__(THREADS, 2) void uparam_kernel(
    const float* __restrict__ params,
    const float* __restrict__ state_re,
    const float* __restrict__ state_im,
    float* __restrict__ out)
{
    __shared__ float lds[LDS_FLOATS];

    const int tid  = threadIdx.x;
    const int item = tid >> 4;     // 0..7 within block
    const int r    = tid & 15;     // column during build, row during matmuls
    const long b   = (long)blockIdx.x * ITEMS + item;

    float* slot = lds + item * UITEM;

    // ---------- Phase P: cooperative sincos table ---------------------------
    // 16 threads per item, 15 angles each; reads 64B-contiguous per group.
    {
        const float* prow = params + b * (2 * NE);
        #pragma unroll
        for (int k = 0; k < 15; ++k) {
            const int a = k * 16 + r;          // 0..239
            const float ang = prow[a];
            float s, c;
            __sincosf(ang, &s, &c);
            const int e   = (a < NE) ? a : a - NE;
            const int off = (a < NE) ? 0 : 2;
            *(float2*)(slot + 4 * e + off) = make_float2(c, s);
        }
    }
    __syncthreads();

    // ---------- Phase B: build U column `r` in registers --------------------
    float Ur[DIM], Ui[DIM];
    #pragma unroll
    for (int i = 0; i < DIM; ++i) { Ur[i] = (i == r) ? 1.0f : 0.0f; Ui[i] = 0.0f; }

    #pragma unroll 1
    for (int l2 = 0; l2 < 8; ++l2) {
        const int eb = l2 * 15;   // 8 even-layer + 7 odd-layer edges per layer pair
        #pragma unroll
        for (int j = 0; j < 15; ++j) {
            // j<8: even layer pair (2j, 2j+1); j>=8: odd layer pair (2(j-8)+1, +2)
            const int m = (j < 8) ? 2 * j : 2 * (j - 8) + 1;
            const int n = m + 1;
            const float4 cs = *(const float4*)(slot + 4 * (eb + j));
            const float c = cs.x, s = cs.y, cp = cs.z, sp = cs.w;
            const float rmr = Ur[m], rmi = Ui[m], rnr = Ur[n], rni = Ui[n];
            // w = e^{i phi} * rm
            const float wr = cp * rmr - sp * rmi;
            const float wi = cp * rmi + sp * rmr;
            Ur[m] = c * wr - s * rnr;
            Ui[m] = c * wi - s * rni;
            Ur[n] = s * wr + c * rnr;
            Ui[n] = s * wi + c * rni;
        }
    }

    __syncthreads();   // cs-table fully consumed; safe to overwrite with U

    // ---------- write U (this lane's column) to LDS --------------------------
    #pragma unroll
    for (int i = 0; i < DIM; ++i) {
        slot[i * USTRIDE + r] = Ur[i];
        slot[DIM * USTRIDE + i * USTRIDE + r] = Ui[i];
    }
    __syncthreads();

    // ---------- Phase C: left row r = U[r][:] * rho --------------------------
    float Lr[DIM], Li[DIM];
    #pragma unroll
    for (int k = 0; k < DIM; ++k) { Lr[k] = 0.f; Li[k] = 0.f; }

    const float4* rhor = (const float4*)(state_re + b * (DIM * DIM));
    const float4* rhoi = (const float4*)(state_im + b * (DIM * DIM));
    const float* Urow_r = slot + r * USTRIDE;
    const float* Urow_i = slot + DIM * USTRIDE + r * USTRIDE;

    #pragma unroll 1
    for (int j4 = 0; j4 < 4; ++j4) {
        const float4 u4r = *(const float4*)(Urow_r + j4 * 4);
        const float4 u4i = *(const float4*)(Urow_i + j4 * 4);
        const float uar[4] = { u4r.x, u4r.y, u4r.z, u4r.w };
        const float uai[4] = { u4i.x, u4i.y, u4i.z, u4i.w };
        #pragma unroll
        for (int jj = 0; jj < 4; ++jj) {
            const int j = j4 * 4 + jj;
            const float ur = uar[jj], ui = uai[jj];
            #pragma unroll
            for (int k4 = 0; k4 < 4; ++k4) {
                const float4 pr = rhor[j * 4 + k4];
                const float4 pi = rhoi[j * 4 + k4];
                Lr[k4*4+0] += ur * pr.x - ui * pi.x;  Li[k4*4+0] += ur * pi.x + ui * pr.x;
                Lr[k4*4+1] += ur * pr.y - ui * pi.y;  Li[k4*4+1] += ur * pi.y + ui * pr.y;
                Lr[k4*4+2] += ur * pr.z - ui * pi.z;  Li[k4*4+2] += ur * pi.z + ui * pr.z;
                Lr[k4*4+3] += ur * pr.w - ui * pi.w;  Li[k4*4+3] += ur * pi.w + ui * pr.w;
            }
        }
    }

    // ---------- Phase D: out[r][j] = sum_k left[k] * conj(U[j][k]) -----------
    float* outp = out + b * (2 * DIM * DIM) + r * DIM;
    #pragma unroll 1
    for (int jj = 0; jj < 4; ++jj) {
        float orr[4], oii[4];
        #pragma unroll
        for (int j4 = 0; j4 < 4; ++j4) {
            const int j = jj * 4 + j4;
            const float* Uj_r = slot + j * USTRIDE;
            const float* Uj_i = slot + DIM * USTRIDE + j * USTRIDE;
            float ar = 0.f, ai = 0.f;
            #pragma unroll
            for (int k4 = 0; k4 < 4; ++k4) {
                const float4 ur4 = *(const float4*)(Uj_r + k4 * 4);
                const float4 ui4 = *(const float4*)(Uj_i + k4 * 4);
                ar += Lr[k4*4+0] * ur4.x + Li[k4*4+0] * ui4.x;
                ai += Li[k4*4+0] * ur4.x - Lr[k4*4+0] * ui4.x;
                ar += Lr[k4*4+1] * ur4.y + Li[k4*4+1] * ui4.y;
                ai += Li[k4*4+1] * ur4.y - Lr[k4*4+1] * ui4.y;
                ar += Lr[k4*4+2] * ur4.z + Li[k4*4+2] * ui4.z;
                ai += Li[k4*4+2] * ur4.z - Lr[k4*4+2] * ui4.z;
                ar += Lr[k4*4+3] * ur4.w + Li[k4*4+3] * ui4.w;
                ai += Li[k4*4+3] * ur4.w - Lr[k4*4+3] * ui4.w;
            }
            orr[j4] = ar; oii[j4] = ai;
        }
        *(float4*)(outp + jj * 4) = make_float4(orr[0], orr[1], orr[2], orr[3]);
        *(float4*)(outp + DIM * DIM + jj * 4) = make_float4(oii[0], oii[1], oii[2], oii[3]);
    }
}

extern "C" void kernel_launch(void* const* d_in, const int* in_sizes, int n_in,
                              void* d_out, int out_size, void* d_ws, size_t ws_size,
                              hipStream_t stream) {
    const float* params   = (const float*)d_in[0];
    const float* state_re = (const float*)d_in[1];
    const float* state_im = (const float*)d_in[2];
    // d_in[3] = targets; structure is the fixed Clements mesh, derived in-kernel.
    float* out = (float*)d_out;

    const int batch = in_sizes[0] / (2 * NE);   // 32768
    dim3 grid(batch / ITEMS);                   // 4096 blocks
    uparam_kernel<<<grid, THREADS, 0, stream>>>(params, state_re, state_im, out);
}

// Round 5
// 78.491 us; speedup vs baseline: 3.2758x; 1.7243x over previous
//
#include <hip/hip_runtime.h>

#define DIM 16
#define NE 120            // edges in the Clements mesh for MODES=16
#define ITEMS 8           // batch items per block
#define THREADS 128
#define USTRIDE 20        // U row stride (floats) -> 80B rows, 16B aligned
#define UITEM 640         // per-item LDS floats; 8 blocks * 20480B = 160KB exactly
#define LDS_FLOATS (ITEMS * UITEM)   // 5120 floats = 20480 B -> 8 blocks/CU

typedef float v2f __attribute__((ext_vector_type(2)));

// Per-item slot layout (lifetimes overlap; cs-table dead before U is written):
//   phase P/B: cs-table record e at cst[4e..4e+3] = {cos t, sin t, cos p, sin p},
//              cst = slot + 8*(item&3)  (32B rotation -> the 4 groups of a wave
//              broadcast-read from distinct bank quads)
//   phase C/D: U: Ure[i] at slot[i*20 + c], Uim[i] at slot[320 + i*20 + c]

__global__ __launch_bounds__(THREADS, 2) void uparam_kernel(
    const float* __restrict__ params,
    const float* __restrict__ state_re,
    const float* __restrict__ state_im,
    float* __restrict__ out)
{
    __shared__ float lds[LDS_FLOATS];

    const int tid  = threadIdx.x;
    const int item = tid >> 4;     // 0..7 within block
    const int r    = tid & 15;     // column during build, row during matmuls
    const long b   = (long)blockIdx.x * ITEMS + item;

    float* slot = lds + item * UITEM;
    float* cst  = slot + 8 * (item & 3);   // rotated cs-table base (480 floats used)

    // ---------- Phase P: cooperative sincos table ---------------------------
    {
        const float* prow = params + b * (2 * NE);
        #pragma unroll
        for (int k = 0; k < 15; ++k) {
            const int a = k * 16 + r;          // 0..239
            float s, c;
            __sincosf(prow[a], &s, &c);
            const int e   = (a < NE) ? a : a - NE;
            const int off = (a < NE) ? 0 : 2;
            *(float2*)(cst + 4 * e + off) = make_float2(c, s);
        }
    }
    __syncthreads();

    // ---------- Phase B: build U column `r` in registers --------------------
    float Ur[DIM], Ui[DIM];
    #pragma unroll
    for (int i = 0; i < DIM; ++i) { Ur[i] = (i == r) ? 1.0f : 0.0f; Ui[i] = 0.0f; }

    #pragma unroll 1
    for (int l2 = 0; l2 < 8; ++l2) {
        const int eb = l2 * 15;   // 8 even-layer + 7 odd-layer edges per layer pair
        #pragma unroll
        for (int j = 0; j < 15; ++j) {
            // j<8: even layer pair (2j, 2j+1); j>=8: odd layer pair (2(j-8)+1, +2)
            const int m = (j < 8) ? 2 * j : 2 * (j - 8) + 1;
            const int n = m + 1;
            const float4 cs = *(const float4*)(cst + 4 * (eb + j));
            const float c = cs.x, s = cs.y, cp = cs.z, sp = cs.w;
            const float rmr = Ur[m], rmi = Ui[m], rnr = Ur[n], rni = Ui[n];
            // w = e^{i phi} * rm
            const float wr = cp * rmr - sp * rmi;
            const float wi = cp * rmi + sp * rmr;
            Ur[m] = c * wr - s * rnr;
            Ui[m] = c * wi - s * rni;
            Ur[n] = s * wr + c * rnr;
            Ui[n] = s * wi + c * rni;
        }
    }

    __syncthreads();   // cs-table fully consumed; safe to overwrite with U

    // ---------- write U (this lane's column) to LDS --------------------------
    #pragma unroll
    for (int i = 0; i < DIM; ++i) {
        slot[i * USTRIDE + r] = Ur[i];
        slot[DIM * USTRIDE + i * USTRIDE + r] = Ui[i];
    }
    __syncthreads();

    // ---------- Phase C: left row r = U[r][:] * rho (packed fp32) ------------
    v2f Lr2[8], Li2[8];
    #pragma unroll
    for (int k = 0; k < 8; ++k) { Lr2[k] = (v2f)(0.0f); Li2[k] = (v2f)(0.0f); }

    const float4* rhor = (const float4*)(state_re + b * (DIM * DIM));
    const float4* rhoi = (const float4*)(state_im + b * (DIM * DIM));
    const float* Urow_r = slot + r * USTRIDE;
    const float* Urow_i = slot + DIM * USTRIDE + r * USTRIDE;

    #pragma unroll 1
    for (int j4 = 0; j4 < 4; ++j4) {
        const float4 u4r = *(const float4*)(Urow_r + j4 * 4);
        const float4 u4i = *(const float4*)(Urow_i + j4 * 4);
        const float uar[4] = { u4r.x, u4r.y, u4r.z, u4r.w };
        const float uai[4] = { u4i.x, u4i.y, u4i.z, u4i.w };
        #pragma unroll
        for (int jj = 0; jj < 4; ++jj) {
            const int j = j4 * 4 + jj;
            const v2f ur2 = { uar[jj], uar[jj] };
            const v2f ui2 = { uai[jj], uai[jj] };
            #pragma unroll
            for (int k4 = 0; k4 < 4; ++k4) {
                const float4 pr = rhor[j * 4 + k4];
                const float4 pi = rhoi[j * 4 + k4];
                const v2f pr0 = { pr.x, pr.y }, pr1 = { pr.z, pr.w };
                const v2f pi0 = { pi.x, pi.y }, pi1 = { pi.z, pi.w };
                Lr2[2*k4+0] = Lr2[2*k4+0] + ur2 * pr0 - ui2 * pi0;
                Lr2[2*k4+1] = Lr2[2*k4+1] + ur2 * pr1 - ui2 * pi1;
                Li2[2*k4+0] = Li2[2*k4+0] + ur2 * pi0 + ui2 * pr0;
                Li2[2*k4+1] = Li2[2*k4+1] + ur2 * pi1 + ui2 * pr1;
            }
        }
    }

    // ---------- Phase D: out[r][j] = sum_k left[k] * conj(U[j][k]) -----------
    float* outp = out + b * (2 * DIM * DIM) + r * DIM;
    #pragma unroll 1
    for (int jj = 0; jj < 4; ++jj) {
        float orr[4], oii[4];
        #pragma unroll
        for (int j4 = 0; j4 < 4; ++j4) {
            const int j = jj * 4 + j4;
            const float* Uj_r = slot + j * USTRIDE;
            const float* Uj_i = slot + DIM * USTRIDE + j * USTRIDE;
            v2f ar2 = (v2f)(0.0f), ai2 = (v2f)(0.0f);
            #pragma unroll
            for (int k4 = 0; k4 < 4; ++k4) {
                const float4 ur4 = *(const float4*)(Uj_r + k4 * 4);
                const float4 ui4 = *(const float4*)(Uj_i + k4 * 4);
                const v2f ur0 = { ur4.x, ur4.y }, ur1 = { ur4.z, ur4.w };
                const v2f ui0 = { ui4.x, ui4.y }, ui1 = { ui4.z, ui4.w };
                ar2 = ar2 + Lr2[2*k4+0] * ur0 + Li2[2*k4+0] * ui0;
                ar2 = ar2 + Lr2[2*k4+1] * ur1 + Li2[2*k4+1] * ui1;
                ai2 = ai2 + Li2[2*k4+0] * ur0 - Lr2[2*k4+0] * ui0;
                ai2 = ai2 + Li2[2*k4+1] * ur1 - Lr2[2*k4+1] * ui1;
            }
            orr[j4] = ar2.x + ar2.y;
            oii[j4] = ai2.x + ai2.y;
        }
        *(float4*)(outp + jj * 4) = make_float4(orr[0], orr[1], orr[2], orr[3]);
        *(float4*)(outp + DIM * DIM + jj * 4) = make_float4(oii[0], oii[1], oii[2], oii[3]);
    }
}

extern "C" void kernel_launch(void* const* d_in, const int* in_sizes, int n_in,
                              void* d_out, int out_size, void* d_ws, size_t ws_size,
                              hipStream_t stream) {
    const float* params   = (const float*)d_in[0];
    const float* state_re = (const float*)d_in[1];
    const float* state_im = (const float*)d_in[2];
    // d_in[3] = targets; structure is the fixed Clements mesh, derived in-kernel.
    float* out = (float*)d_out;

    const int batch = in_sizes[0] / (2 * NE);   // 32768
    dim3 grid(batch / ITEMS);                   // 4096 blocks
    uparam_kernel<<<grid, THREADS, 0, stream>>>(params, state_re, state_im, out);
}

// Round 6
// 65.433 us; speedup vs baseline: 3.9295x; 1.1996x over previous
//
#include <hip/hip_runtime.h>

#define DIM 16
#define NE 120            // edges in the Clements mesh for MODES=16
#define ITEMS 4           // batch items per block (one wave)
#define THREADS 64
#define USTRIDE 20        // U row stride (floats) -> 80B rows, 16B aligned
#define UITEM 648         // per-item LDS floats; == 8 mod 32 -> groups on rotated banks
#define LDS_FLOATS (ITEMS * UITEM)   // 2592 floats = 10368 B -> 15 blocks/CU

typedef float v2f __attribute__((ext_vector_type(2)));

// Per-item slot layout (lifetimes overlap; cs-table dead before U is written):
//   phase P/B: cs record e at slot[4e..4e+3] = {cos t, sin t, cos p, sin p}   (480 floats)
//   phase C/D: U: Ure[i] at slot[i*20 + c], Uim[i] at slot[320 + i*20 + c]    (640 floats)

__global__ __launch_bounds__(THREADS, 2) void uparam_kernel(
    const float* __restrict__ params,
    const float* __restrict__ state_re,
    const float* __restrict__ state_im,
    float* __restrict__ out)
{
    __shared__ float lds[LDS_FLOATS];

    const int tid  = threadIdx.x;
    const int item = tid >> 4;     // 0..3 within the wave
    const int r    = tid & 15;     // column during build, row during matmuls
    const long b   = (long)blockIdx.x * ITEMS + item;

    float* slot = lds + item * UITEM;

    // ---------- Phase P: cooperative sincos table ---------------------------
    {
        const float* prow = params + b * (2 * NE);
        #pragma unroll
        for (int k = 0; k < 15; ++k) {
            const int a = k * 16 + r;          // 0..239
            float s, c;
            __sincosf(prow[a], &s, &c);
            const int e   = (a < NE) ? a : a - NE;
            const int off = (a < NE) ? 0 : 2;
            *(float2*)(slot + 4 * e + off) = make_float2(c, s);
        }
    }

    const float4* rhor = (const float4*)(state_re + b * (DIM * DIM));
    const float4* rhoi = (const float4*)(state_im + b * (DIM * DIM));

    // Preload rho row 0 (latency hides under phase B)
    float4 Ar0 = rhor[0], Ar1 = rhor[1], Ar2 = rhor[2], Ar3 = rhor[3];
    float4 Ai0 = rhoi[0], Ai1 = rhoi[1], Ai2 = rhoi[2], Ai3 = rhoi[3];

    __syncthreads();

    // ---------- Phase B: build U column `r`, packed complex -----------------
    v2f Uv[DIM];
    #pragma unroll
    for (int i = 0; i < DIM; ++i) Uv[i] = (v2f){ (i == r) ? 1.0f : 0.0f, 0.0f };

    #pragma unroll 1
    for (int l2 = 0; l2 < 8; ++l2) {
        const int eb = l2 * 15;
        #pragma unroll
        for (int j = 0; j < 15; ++j) {
            const int m = (j < 8) ? 2 * j : 2 * (j - 8) + 1;
            const int n = m + 1;
            const float4 cs = *(const float4*)(slot + 4 * (eb + j));
            const float c = cs.x, s = cs.y, cp = cs.z, sp = cs.w;
            const v2f um = Uv[m], un = Uv[n];
            const v2f jm = { -um.y, um.x };      // i * um
            const v2f w  = cp * um + sp * jm;    // e^{i phi} * um
            Uv[m] = c * w - s * un;
            Uv[n] = s * w + c * un;
        }
    }
    __syncthreads();   // cs-table fully consumed

    // ---------- write U (this lane's column) to LDS --------------------------
    #pragma unroll
    for (int i = 0; i < DIM; ++i) {
        slot[i * USTRIDE + r] = Uv[i].x;
        slot[DIM * USTRIDE + i * USTRIDE + r] = Uv[i].y;
    }
    __syncthreads();

    // ---------- Phase C: left row r = U[r][:] * rho, row-pipelined -----------
    v2f Lr2[8], Li2[8];
    #pragma unroll
    for (int k = 0; k < 8; ++k) { Lr2[k] = (v2f)(0.0f); Li2[k] = (v2f)(0.0f); }

    const float* Urow_r = slot + r * USTRIDE;
    const float* Urow_i = slot + DIM * USTRIDE + r * USTRIDE;

    float4 Br0, Br1, Br2, Br3, Bi0, Bi1, Bi2, Bi3;

#define LOADA(J) do { Ar0=rhor[(J)*4]; Ar1=rhor[(J)*4+1]; Ar2=rhor[(J)*4+2]; Ar3=rhor[(J)*4+3]; \
                      Ai0=rhoi[(J)*4]; Ai1=rhoi[(J)*4+1]; Ai2=rhoi[(J)*4+2]; Ai3=rhoi[(J)*4+3]; } while(0)
#define LOADB(J) do { Br0=rhor[(J)*4]; Br1=rhor[(J)*4+1]; Br2=rhor[(J)*4+2]; Br3=rhor[(J)*4+3]; \
                      Bi0=rhoi[(J)*4]; Bi1=rhoi[(J)*4+1]; Bi2=rhoi[(J)*4+2]; Bi3=rhoi[(J)*4+3]; } while(0)

    auto upd = [&](const float4 R0, const float4 R1, const float4 R2, const float4 R3,
                   const float4 I0, const float4 I1, const float4 I2, const float4 I3,
                   const float ur, const float ui) {
        const v2f u_r = { ur, ur }, u_i = { ui, ui };
        Lr2[0] += u_r * (v2f){R0.x, R0.y} - u_i * (v2f){I0.x, I0.y};
        Lr2[1] += u_r * (v2f){R0.z, R0.w} - u_i * (v2f){I0.z, I0.w};
        Lr2[2] += u_r * (v2f){R1.x, R1.y} - u_i * (v2f){I1.x, I1.y};
        Lr2[3] += u_r * (v2f){R1.z, R1.w} - u_i * (v2f){I1.z, I1.w};
        Lr2[4] += u_r * (v2f){R2.x, R2.y} - u_i * (v2f){I2.x, I2.y};
        Lr2[5] += u_r * (v2f){R2.z, R2.w} - u_i * (v2f){I2.z, I2.w};
        Lr2[6] += u_r * (v2f){R3.x, R3.y} - u_i * (v2f){I3.x, I3.y};
        Lr2[7] += u_r * (v2f){R3.z, R3.w} - u_i * (v2f){I3.z, I3.w};
        Li2[0] += u_r * (v2f){I0.x, I0.y} + u_i * (v2f){R0.x, R0.y};
        Li2[1] += u_r * (v2f){I0.z, I0.w} + u_i * (v2f){R0.z, R0.w};
        Li2[2] += u_r * (v2f){I1.x, I1.y} + u_i * (v2f){R1.x, R1.y};
        Li2[3] += u_r * (v2f){I1.z, I1.w} + u_i * (v2f){R1.z, R1.w};
        Li2[4] += u_r * (v2f){I2.x, I2.y} + u_i * (v2f){R2.x, R2.y};
        Li2[5] += u_r * (v2f){I2.z, I2.w} + u_i * (v2f){R2.z, R2.w};
        Li2[6] += u_r * (v2f){I3.x, I3.y} + u_i * (v2f){R3.x, R3.y};
        Li2[7] += u_r * (v2f){I3.z, I3.w} + u_i * (v2f){R3.z, R3.w};
    };

    #pragma unroll 1
    for (int j4 = 0; j4 < 3; ++j4) {
        const float4 u4r = *(const float4*)(Urow_r + 4 * j4);
        const float4 u4i = *(const float4*)(Urow_i + 4 * j4);
        LOADB(4 * j4 + 1);
        upd(Ar0, Ar1, Ar2, Ar3, Ai0, Ai1, Ai2, Ai3, u4r.x, u4i.x);
        LOADA(4 * j4 + 2);
        upd(Br0, Br1, Br2, Br3, Bi0, Bi1, Bi2, Bi3, u4r.y, u4i.y);
        LOADB(4 * j4 + 3);
        upd(Ar0, Ar1, Ar2, Ar3, Ai0, Ai1, Ai2, Ai3, u4r.z, u4i.z);
        LOADA(4 * j4 + 4);
        upd(Br0, Br1, Br2, Br3, Bi0, Bi1, Bi2, Bi3, u4r.w, u4i.w);
    }
    {   // tail: rows 12..15 (A holds row 12)
        const float4 u4r = *(const float4*)(Urow_r + 12);
        const float4 u4i = *(const float4*)(Urow_i + 12);
        LOADB(13);
        upd(Ar0, Ar1, Ar2, Ar3, Ai0, Ai1, Ai2, Ai3, u4r.x, u4i.x);
        LOADA(14);
        upd(Br0, Br1, Br2, Br3, Bi0, Bi1, Bi2, Bi3, u4r.y, u4i.y);
        LOADB(15);
        upd(Ar0, Ar1, Ar2, Ar3, Ai0, Ai1, Ai2, Ai3, u4r.z, u4i.z);
        upd(Br0, Br1, Br2, Br3, Bi0, Bi1, Bi2, Bi3, u4r.w, u4i.w);
    }
#undef LOADA
#undef LOADB

    // ---------- Phase D: out[r][j] = sum_k left[k] * conj(U[j][k]) -----------
    float* outp = out + b * (2 * DIM * DIM) + r * DIM;
    #pragma unroll 1
    for (int jj = 0; jj < 4; ++jj) {
        float orr[4], oii[4];
        #pragma unroll
        for (int j4 = 0; j4 < 4; ++j4) {
            const int j = jj * 4 + j4;
            const float* Uj_r = slot + j * USTRIDE;
            const float* Uj_i = slot + DIM * USTRIDE + j * USTRIDE;
            v2f ar2 = (v2f)(0.0f), ai2 = (v2f)(0.0f);
            #pragma unroll
            for (int k4 = 0; k4 < 4; ++k4) {
                const float4 ur4 = *(const float4*)(Uj_r + k4 * 4);
                const float4 ui4 = *(const float4*)(Uj_i + k4 * 4);
                const v2f ur0 = { ur4.x, ur4.y }, ur1 = { ur4.z, ur4.w };
                const v2f ui0 = { ui4.x, ui4.y }, ui1 = { ui4.z, ui4.w };
                ar2 = ar2 + Lr2[2*k4+0] * ur0 + Li2[2*k4+0] * ui0;
                ar2 = ar2 + Lr2[2*k4+1] * ur1 + Li2[2*k4+1] * ui1;
                ai2 = ai2 + Li2[2*k4+0] * ur0 - Lr2[2*k4+0] * ui0;
                ai2 = ai2 + Li2[2*k4+1] * ur1 - Lr2[2*k4+1] * ui1;
            }
            orr[j4] = ar2.x + ar2.y;
            oii[j4] = ai2.x + ai2.y;
        }
        *(float4*)(outp + jj * 4) = make_float4(orr[0], orr[1], orr[2], orr[3]);
        *(float4*)(outp + DIM * DIM + jj * 4) = make_float4(oii[0], oii[1], oii[2], oii[3]);
    }
}

extern "C" void kernel_launch(void* const* d_in, const int* in_sizes, int n_in,
                              void* d_out, int out_size, void* d_ws, size_t ws_size,
                              hipStream_t stream) {
    const float* params   = (const float*)d_in[0];
    const float* state_re = (const float*)d_in[1];
    const float* state_im = (const float*)d_in[2];
    // d_in[3] = targets; structure is the fixed Clements mesh, derived in-kernel.
    float* out = (float*)d_out;

    const int batch = in_sizes[0] / (2 * NE);   // 32768
    dim3 grid(batch / ITEMS);                   // 8192 blocks, 1 wave each
    uparam_kernel<<<grid, THREADS, 0, stream>>>(params, state_re, state_im, out);
}